// Round 16
// baseline (459.717 us; speedup 1.0000x reference)
//
#include <hip/hip_runtime.h>

#define VOCAB 512
#define EMB   128
#define HID   64
#define BATCH 256
#define TLEN  1024
#define CH    16              // steps per chunk
#define NCH   (TLEN / CH)     // 64 chunks
#define RS    64              // a_ring depth in steps
#define RCH   (RS / CH)       // 4 chunks per ring
#define RW    96              // swizzled row width (floats): seg kg at 24*kg
                              // (R22-audited: banks covered exactly 2-way)

typedef float v2f __attribute__((ext_vector_type(2)));

__device__ __forceinline__ float fast_tanh(float x) {
    // tanh(x) = 1 - 2/(exp(2x)+1); exact at both saturated ends.
    float e = __expf(2.0f * x);
    return 1.0f - 2.0f / (e + 1.0f);
}
__device__ __forceinline__ void lds_fence() {
    asm volatile("s_waitcnt lgkmcnt(0)" ::: "memory");
}
__device__ __forceinline__ void compiler_fence() {
    asm volatile("" ::: "memory");
}
__device__ __forceinline__ void nap() { __builtin_amdgcn_s_sleep(1); }

__device__ __forceinline__ float dpp_xor1(float x) {    // quad_perm [1,0,3,2]
    return __int_as_float(__builtin_amdgcn_update_dpp(
        0, __float_as_int(x), 0xB1, 0xF, 0xF, false));
}
__device__ __forceinline__ float dpp_xor2(float x) {    // quad_perm [2,3,0,1]
    return __int_as_float(__builtin_amdgcn_update_dpp(
        0, __float_as_int(x), 0x4E, 0xF, 0xF, false));
}

// 2-stage butterfly reduce-scatter across the quad (R21-proven): input
// p[0..3] = this lane's partial for rows o+16*{0,1,2,3}; returns the FULL
// quad-sum for row o+16*kg in each lane.
__device__ __forceinline__ float quad_rs(const float p[4], bool b0, bool b1m) {
    float x01 = b0 ? p[1] : p[0];
    float y01 = b0 ? p[0] : p[1];
    x01 += dpp_xor1(y01);
    float x23 = b0 ? p[3] : p[2];
    float y23 = b0 ? p[2] : p[3];
    x23 += dpp_xor1(y23);
    float u = b1m ? x23 : x01;
    float v = b1m ? x01 : x23;
    return u + dpp_xor2(v);
}

// 4-lane cooperative 64-dot (R21-proven): lane (o=lane>>2, kg=lane&3)
// holds rows {o+16r} x cols [16kg,16kg+16).
__device__ __forceinline__ float dot_seg_rs(const float4 s[4],
                                            const v2f w[4][8],
                                            bool b0, bool b1m) {
    float p[4];
    #pragma unroll
    for (int r = 0; r < 4; ++r) {
        v2f a0 = v2f{0.f, 0.f}, a1 = v2f{0.f, 0.f};
        #pragma unroll
        for (int c = 0; c < 4; ++c) {
            float4 u = s[c];
            a0 = __builtin_elementwise_fma(v2f{u.x, u.y}, w[r][2 * c],     a0);
            a1 = __builtin_elementwise_fma(v2f{u.z, u.w}, w[r][2 * c + 1], a1);
        }
        v2f t = a0 + a1;
        p[r] = t.x + t.y;
    }
    return quad_rs(p, b0, b1m);
}

// Fused two-input dot (R23): p[r] = wB[r]·s0 + wC[r]·s1, ONE reduce-scatter.
// This is the h1-half of the 128-wide step: Wih1*h0part + Whh1*h1part.
__device__ __forceinline__ float dot2_seg_rs(const float4 s0[4],
                                             const v2f wB[4][8],
                                             const float4 s1[4],
                                             const v2f wC[4][8],
                                             bool b0, bool b1m) {
    float p[4];
    #pragma unroll
    for (int r = 0; r < 4; ++r) {
        v2f a0 = v2f{0.f, 0.f}, a1 = v2f{0.f, 0.f};
        #pragma unroll
        for (int c = 0; c < 4; ++c) {
            float4 u = s0[c];
            a0 = __builtin_elementwise_fma(v2f{u.x, u.y}, wB[r][2 * c],     a0);
            a1 = __builtin_elementwise_fma(v2f{u.z, u.w}, wB[r][2 * c + 1], a1);
        }
        #pragma unroll
        for (int c = 0; c < 4; ++c) {
            float4 u = s1[c];
            a0 = __builtin_elementwise_fma(v2f{u.x, u.y}, wC[r][2 * c],     a0);
            a1 = __builtin_elementwise_fma(v2f{u.z, u.w}, wC[r][2 * c + 1], a1);
        }
        v2f t = a0 + a1;
        p[r] = t.x + t.y;
    }
    return quad_rs(p, b0, b1m);
}

__device__ __forceinline__ void load_w(v2f w[4][8], const float* __restrict__ W,
                                       int o, int kg) {
    #pragma unroll
    for (int r = 0; r < 4; ++r) {
        const float4* wr = (const float4*)(W + (o + 16 * r) * HID + 16 * kg);
        #pragma unroll
        for (int c = 0; c < 4; ++c) {
            float4 u = wr[c];
            w[r][2 * c]     = v2f{u.x, u.y};
            w[r][2 * c + 1] = v2f{u.z, u.w};
        }
    }
}

// Load this lane's 16-float segment (4x ds_read_b128; starts at banks
// {0,24,16,8} with the RW=96 layout -> disjoint spans, conflict-free).
__device__ __forceinline__ void seg_load(float4 s[4], const float* rowkg) {
    const float4* p = (const float4*)rowkg;
    #pragma unroll
    for (int c = 0; c < 4; ++c) s[c] = p[c];
}

// ---------------------------------------------------------------------------
// Kernel 1: P0[v][i] = sum_e emb[v][e]*Wih0[i][e] + bih0[i] + bhh0[i]  (fp32)
// ---------------------------------------------------------------------------
__global__ void __launch_bounds__(64) p0_kernel(
    const float* __restrict__ emb,
    const float* __restrict__ wih0,
    const float* __restrict__ bih0,
    const float* __restrict__ bhh0,
    float* __restrict__ P0)
{
    const int v = blockIdx.x;
    const int i = threadIdx.x;
    const float4* er = (const float4*)(emb  + v * EMB);
    const float4* wr = (const float4*)(wih0 + i * EMB);
    float a0 = 0.f, a1 = 0.f, a2 = 0.f, a3 = 0.f;
    #pragma unroll
    for (int k = 0; k < EMB / 4; ++k) {
        float4 e4 = er[k];
        float4 w4 = wr[k];
        a0 = fmaf(e4.x, w4.x, a0);
        a1 = fmaf(e4.y, w4.y, a1);
        a2 = fmaf(e4.z, w4.z, a2);
        a3 = fmaf(e4.w, w4.w, a3);
    }
    P0[v * HID + i] = (a0 + a1) + (a2 + a3) + bih0[i] + bhh0[i];
}

// ---------------------------------------------------------------------------
// Kernel 2 (R23): SKEWED-STATE single recurrence. The two-layer RNN under
// S_t = [h0(t); h1(t-1)] is ONE 128-wide RNN: S_t = tanh(M S_{t-1} + u(t)),
// M = [[Whh0, 0],[Wih1, Whh1]] (block-triangular: 3 64x64 dots/step — the
// same three dots that R17-R22 spread over 3 pipelined waves). One compute
// wave = one RTT per step, ZERO inter-wave handoffs on the chain, 2 DS
// clients instead of 4. Boundary: h1-half forced to 0 at t=0 (= h1(-1));
// epilogue computes h1(1023); MLP head in-wave.
//   wave0 : S_t step (dotA = Whh0*h0part + a; dotBC = Wih1*h0part+Whh1*h1part)
//   wave1 : feeder a[t][row] = P0[x[t]][row] -> a_ring  (off-chain)
// ---------------------------------------------------------------------------
__global__ void __launch_bounds__(128, 1) rnn_kernel(
    const int*   __restrict__ xs,
    const float* __restrict__ P0,
    const float* __restrict__ Whh0,
    const float* __restrict__ Wih1,
    const float* __restrict__ Whh1,
    const float* __restrict__ bih1,
    const float* __restrict__ bhh1,
    const float* __restrict__ W1,
    const float* __restrict__ b1,
    const float* __restrict__ W2,
    const float* __restrict__ b2,
    float*       __restrict__ out)
{
    __shared__ float a_ring[RS][HID];   // 16 KiB; [t][row] = P0[x[t]][row]
    __shared__ float sring[2][2][RW];   // 3 KiB; [parity][half][swizzled row]
    __shared__ int   flags[2];

    const int b    = blockIdx.x;
    const int tid  = threadIdx.x;
    const int wv   = tid >> 6;
    const int lane = tid & 63;
    const int o    = lane >> 2;         // output group (0..15)
    const int kg   = lane & 3;          // k-segment   (0..3)
    const int row  = o + 16 * kg;       // output row this lane owns
    const int wrs  = 24 * kg + o;       // swizzled write slot for `row`
    const bool b0  = (kg & 1) != 0;     // reduce-scatter keep/send selects
    const bool b1m = (kg & 2) != 0;

    const int* xrow = xs + b * TLEN;
    // vz == 0, but opaque to uniformity analysis -> forces VECTOR loads
    // (vmcnt path) for the x reads instead of s_load (lgkmcnt path).
    const int vz = (int)__builtin_amdgcn_mbcnt_lo(0u, 0u);

    if (tid < 2) flags[tid] = 0;
    __syncthreads();                     // the ONLY barrier in the kernel

    volatile int* vf = (volatile int*)flags;
    // vf[0]: compute-wave chunks done (a_ring slot consumed)
    // vf[1]: feeder chunks ready

    if (wv == 0) {
        // ================= wave0: fused 128-wide recurrence ===============
        v2f wA[4][8], wB[4][8], wC[4][8];
        load_w(wA, Whh0, o, kg);         // h0-half rows
        load_w(wB, Wih1, o, kg);         // h1-half, h0-part columns
        load_w(wC, Whh1, o, kg);         // h1-half, h1-part columns
        const float b1s = bih1[row] + bhh1[row];
        __builtin_amdgcn_s_setprio(1);

        float4 sh0[4], sh1[4];           // S_{t-1} segments (regs); S_{-1}=0
        #pragma unroll
        for (int c = 0; c < 4; ++c) {
            sh0[c] = float4{0.f, 0.f, 0.f, 0.f};
            sh1[c] = float4{0.f, 0.f, 0.f, 0.f};
        }

        #pragma unroll 1
        for (int k = 0; k < NCH; ++k) {
            while (vf[1] < k + 1) nap(); // feeder: a_ring chunk k ready
            compiler_fence();
            const int base = (k & (RCH - 1)) * CH;
            float a8[CH];                // bulk a reads (b32, 2-way = free)
            #pragma unroll
            for (int i = 0; i < CH; ++i) a8[i] = a_ring[base + i][row];
            #pragma unroll
            for (int i = 0; i < CH; ++i) {
                const int t = k * CH + i;
                // h0-half: Whh0 * h0part + a(t)
                float zA = dot_seg_rs(sh0, wA, b0, b1m) + a8[i];
                // h1-half: Wih1 * h0part + Whh1 * h1part + b1s (one reduce)
                float zH = dot2_seg_rs(sh0, wB, sh1, wC, b0, b1m) + b1s;
                float h0v = fast_tanh(zA);
                float h1v = (t == 0) ? 0.f : fast_tanh(zH); // h1(-1) = 0
                sring[t & 1][0][wrs] = h0v;       // 2 ds_write_b32
                sring[t & 1][1][wrs] = h1v;
                seg_load(sh0, &sring[t & 1][0][24 * kg]);  // 4 b128
                seg_load(sh1, &sring[t & 1][1][24 * kg]);  // 4 b128
            }
            lds_fence();                 // a reads consumed; ring slot free
            if (lane == 0) vf[0] = k + 1;
        }
        // ---- epilogue step t=TLEN: h1(1023) = h1-half of S_TLEN ----
        float zH = dot2_seg_rs(sh0, wB, sh1, wC, b0, b1m) + b1s;
        float h1f = fast_tanh(zH);
        sring[0][1][wrs] = h1f;          // parity TLEN&1 = 0
        lds_fence();
        // ---- MLP head: y = relu(h1 @ W1^T + b1) @ W2^T + b2 ----
        float r = 0.f;
        if (lane < 32) {
            float acc = b1[lane];
            const float* w1row = W1 + lane * HID;
            const float* hN    = sring[0][1];
            #pragma unroll
            for (int j = 0; j < HID; ++j)
                acc = fmaf(w1row[j], hN[24 * (j >> 4) + (j & 15)], acc);
            r = fmaxf(acc, 0.f) * W2[lane];
        }
        #pragma unroll
        for (int off = 32; off > 0; off >>= 1) r += __shfl_down(r, off);
        if (lane == 0) out[b] = r + b2[0];
    } else {
        // ================= wave1: feeder (x loads + P0 gather) ============
        #pragma unroll 1
        for (int k = 0; k < NCH; ++k) {
            if (k >= RCH) {              // a_ring slot-reuse guard (wave0)
                while (vf[0] < k - (RCH - 1)) nap();
                compiler_fence();
            }
            const int* xp = xrow + k * CH;
            int xv[CH];
            #pragma unroll
            for (int i = 0; i < CH; ++i)
                xv[i] = xp[i + vz] & (VOCAB - 1);
            float av[CH];
            #pragma unroll
            for (int i = 0; i < CH; ++i)
                av[i] = P0[xv[i] * HID + row];
            const int base = (k & (RCH - 1)) * CH;
            #pragma unroll
            for (int i = 0; i < CH; ++i)
                a_ring[base + i][row] = av[i];
            lds_fence();                 // a_ring writes visible
            if (lane == 0) vf[1] = k + 1;
        }
    }
}

extern "C" void kernel_launch(void* const* d_in, const int* in_sizes, int n_in,
                              void* d_out, int out_size, void* d_ws, size_t ws_size,
                              hipStream_t stream)
{
    const int*   x    = (const int*)d_in[0];
    const float* emb  = (const float*)d_in[1];
    const float* Wih0 = (const float*)d_in[2];
    const float* Whh0 = (const float*)d_in[3];
    const float* bih0 = (const float*)d_in[4];
    const float* bhh0 = (const float*)d_in[5];
    const float* Wih1 = (const float*)d_in[6];
    const float* Whh1 = (const float*)d_in[7];
    const float* bih1 = (const float*)d_in[8];
    const float* bhh1 = (const float*)d_in[9];
    const float* W1   = (const float*)d_in[10];
    const float* b1   = (const float*)d_in[11];
    const float* W2   = (const float*)d_in[12];
    const float* b2   = (const float*)d_in[13];

    float* P0 = (float*)d_ws;   // 512*64*4 = 128 KiB scratch

    hipLaunchKernelGGL(p0_kernel, dim3(VOCAB), dim3(HID), 0, stream,
                       emb, Wih0, bih0, bhh0, P0);
    hipLaunchKernelGGL(rnn_kernel, dim3(BATCH), dim3(128), 0, stream,
                       x, P0, Whh0, Wih1, Whh1, bih1, bhh1,
                       W1, b1, W2, b2, (float*)d_out);
}

// Round 17
// 286.185 us; speedup vs baseline: 1.6064x; 1.6064x over previous
//
#include <hip/hip_runtime.h>

#define VOCAB 512
#define EMB   128
#define HID   64
#define BATCH 256
#define TLEN  1024
#define CH    16              // steps per chunk (16: poll overhead halved, I-cache safe)
#define NCH   (TLEN / CH)     // 64 chunks
#define RS    64              // ring depth in steps
#define RCH   (RS / CH)       // 4 chunks per ring
#define RW    96              // swizzled row width (floats): seg kg at 24*kg
                              // (R22-audited: banks covered exactly 2-way)

typedef float v2f __attribute__((ext_vector_type(2)));

__device__ __forceinline__ float fast_tanh(float x) {
    // tanh(x) = 1 - 2/(exp(2x)+1); exact at both saturated ends.
    float e = __expf(2.0f * x);
    return 1.0f - 2.0f / (e + 1.0f);
}
__device__ __forceinline__ void lds_fence() {
    asm volatile("s_waitcnt lgkmcnt(0)" ::: "memory");
}
__device__ __forceinline__ void compiler_fence() {
    asm volatile("" ::: "memory");
}
__device__ __forceinline__ void nap() { __builtin_amdgcn_s_sleep(1); }

__device__ __forceinline__ float dpp_xor1(float x) {    // quad_perm [1,0,3,2]
    return __int_as_float(__builtin_amdgcn_update_dpp(
        0, __float_as_int(x), 0xB1, 0xF, 0xF, false));
}
__device__ __forceinline__ float dpp_xor2(float x) {    // quad_perm [2,3,0,1]
    return __int_as_float(__builtin_amdgcn_update_dpp(
        0, __float_as_int(x), 0x4E, 0xF, 0xF, false));
}

// 4-lane cooperative 64-dot with REDUCE-SCATTER finish (R21-proven).
// Lane (o=lane>>2, kg=lane&3) holds rows {o+16r} x cols [16kg,16kg+16).
// 2-stage butterfly gives each lane ITS row's full sum directly.
__device__ __forceinline__ float dot_seg_rs(const float4 s[4],
                                            const v2f w[4][8],
                                            bool b0, bool b1m) {
    float p[4];
    #pragma unroll
    for (int r = 0; r < 4; ++r) {
        v2f a0 = v2f{0.f, 0.f}, a1 = v2f{0.f, 0.f};
        #pragma unroll
        for (int c = 0; c < 4; ++c) {
            float4 u = s[c];
            a0 = __builtin_elementwise_fma(v2f{u.x, u.y}, w[r][2 * c],     a0);
            a1 = __builtin_elementwise_fma(v2f{u.z, u.w}, w[r][2 * c + 1], a1);
        }
        v2f t = a0 + a1;
        p[r] = t.x + t.y;
    }
    // stage 1 (partner ^1): keep row (kg&1) of pair {0,1} and of pair {2,3}
    float x01 = b0 ? p[1] : p[0];
    float y01 = b0 ? p[0] : p[1];          // the value the partner needs
    x01 += dpp_xor1(y01);
    float x23 = b0 ? p[3] : p[2];
    float y23 = b0 ? p[2] : p[3];
    x23 += dpp_xor1(y23);
    // stage 2 (partner ^2): keep the (kg&2)-selected half
    float u = b1m ? x23 : x01;
    float v = b1m ? x01 : x23;
    return u + dpp_xor2(v);                // full sum of row o+16*kg
}

__device__ __forceinline__ void load_w(v2f w[4][8], const float* __restrict__ W,
                                       int o, int kg) {
    #pragma unroll
    for (int r = 0; r < 4; ++r) {
        const float4* wr = (const float4*)(W + (o + 16 * r) * HID + 16 * kg);
        #pragma unroll
        for (int c = 0; c < 4; ++c) {
            float4 u = wr[c];
            w[r][2 * c]     = v2f{u.x, u.y};
            w[r][2 * c + 1] = v2f{u.z, u.w};
        }
    }
}

// Load this lane's 16-float segment (4x ds_read_b128). With RW=96 the 4
// kg-addresses start at banks {0,24,16,8}: disjoint 4-bank spans.
__device__ __forceinline__ void seg_load(float4 s[4], const float* rowkg) {
    const float4* p = (const float4*)rowkg;
    #pragma unroll
    for (int c = 0; c < 4; ++c) s[c] = p[c];
}

// ---------------------------------------------------------------------------
// Kernel 1 (R24 rewrite): P0[v][i] = emb[v]·wih0[i] + bih0[i] + bhh0[i]
// Old version read wih0 rows lane-strided (512B apart): every load touched
// 64 cache lines and serialized on a shared bank span. New version stages
// wih0 (32KB) into LDS with COALESCED flat float4 global reads + an XOR
// column swizzle (col4 ^ (row&7)): 16B-aligned, and a wave's 64 b128 reads
// start at disjoint 4-bank spans for lanes 0..7 -> reads run at the 8-cyc
// b128 hardware floor instead of the same-span crawl.
// ---------------------------------------------------------------------------
__global__ void __launch_bounds__(64) p0_kernel(
    const float* __restrict__ emb,
    const float* __restrict__ wih0,
    const float* __restrict__ bih0,
    const float* __restrict__ bhh0,
    float* __restrict__ P0)
{
    __shared__ float4 wl4[HID * 32];     // 32 KiB: wih0 swizzled, row*32+col4s
    const int v    = blockIdx.x;
    const int lane = threadIdx.x;

    // stage: 2048 float4 = 64 lanes x 32 iters, coalesced global reads
    const float4* wsrc = (const float4*)wih0;
    #pragma unroll
    for (int c = 0; c < 32; ++c) {
        const int f    = c * 64 + lane;  // flat float4 index
        const int row  = f >> 5;         // 32 float4 per row
        const int col4 = f & 31;
        wl4[row * 32 + (col4 ^ (row & 7))] = wsrc[f];
    }
    __syncthreads();

    // dot: emb[v] (broadcast loads) . wih0[lane] (swizzled LDS reads)
    const float4* er = (const float4*)(emb + v * EMB);
    const int rbase  = lane * 32;
    const int rx     = lane & 7;
    float a0 = 0.f, a1 = 0.f, a2 = 0.f, a3 = 0.f;
    #pragma unroll
    for (int k = 0; k < EMB / 4; ++k) {
        float4 e4 = er[k];
        float4 w4 = wl4[rbase + (k ^ rx)];
        a0 = fmaf(e4.x, w4.x, a0);
        a1 = fmaf(e4.y, w4.y, a1);
        a2 = fmaf(e4.z, w4.z, a2);
        a3 = fmaf(e4.w, w4.w, a3);
    }
    P0[v * HID + lane] = (a0 + a1) + (a2 + a3) + bih0[lane] + bhh0[lane];
}

// ---------------------------------------------------------------------------
// Kernel 2 (R22-verbatim, 223us best): 4-wave pipeline, RW=96 2-way swizzle.
//   wave0 : h0[t] = tanh(a[t] + Whh0 h0[t-1])       (prio1, a_ring-fed)
//   wave1 : p1[t] = b1 + Wih1 h0[t]                 (prio0)
//   wave2 : h1[t] = tanh(p1[t] + Whh1 h1[t-1])      (prio1) + MLP head
//   wave3 : feeder a[t][row] = P0[x[t]][row]        (prio0, off-chain)
// ---------------------------------------------------------------------------
__global__ void __launch_bounds__(256, 1) rnn_kernel(
    const int*   __restrict__ xs,
    const float* __restrict__ P0,
    const float* __restrict__ Whh0,
    const float* __restrict__ Wih1,
    const float* __restrict__ Whh1,
    const float* __restrict__ bih1,
    const float* __restrict__ bhh1,
    const float* __restrict__ W1,
    const float* __restrict__ b1,
    const float* __restrict__ W2,
    const float* __restrict__ b2,
    float*       __restrict__ out)
{
    __shared__ float a_ring[RS][HID];   // 16 KiB; [t][row] = P0[x[t]][row]
    __shared__ float h0ring[RS][RW];    // 24 KiB, swizzled rows
    __shared__ float p1ring[RS][HID];   // 16 KiB, plain rows
    __shared__ float h1buf[2][RW];      // swizzled
    __shared__ int   flags[4];

    const int b    = blockIdx.x;
    const int tid  = threadIdx.x;
    const int wv   = tid >> 6;
    const int lane = tid & 63;
    const int o    = lane >> 2;         // output group (0..15)
    const int kg   = lane & 3;          // k-segment   (0..3)
    const int row  = o + 16 * kg;       // output row this lane owns
    const int wrs  = 24 * kg + o;       // swizzled write slot for `row`
    const bool b0  = (kg & 1) != 0;     // reduce-scatter keep/send selects
    const bool b1m = (kg & 2) != 0;

    const int* xrow = xs + b * TLEN;
    // vz == 0, but opaque to uniformity analysis -> forces VECTOR loads
    // (vmcnt path) for the x reads instead of s_load (lgkmcnt path).
    const int vz = (int)__builtin_amdgcn_mbcnt_lo(0u, 0u);

    if (tid < 4) flags[tid] = 0;
    __syncthreads();                     // the ONLY barrier in the kernel

    volatile int* vf = (volatile int*)flags;

    if (wv == 0) {
        // ================= wave0: layer-0 recurrence (slim, prio1) ========
        v2f w0[4][8];
        load_w(w0, Whh0, o, kg);
        __builtin_amdgcn_s_setprio(1);

        float4 s0[4];                    // h0[t-1] segment (regs)
        #pragma unroll
        for (int c = 0; c < 4; ++c) s0[c] = float4{0.f, 0.f, 0.f, 0.f};

        #pragma unroll 1
        for (int k = 0; k < NCH; ++k) {
            while (vf[3] < k + 1) nap(); // feeder: a_ring chunk k ready
            if (k >= RCH) {              // h0ring slot-reuse guard (wave1)
                while (vf[1] < k - (RCH - 1)) nap();
            }
            compiler_fence();
            const int base = (k & (RCH - 1)) * CH;
            float a8[CH];                // bulk a reads (b32, 2-way = free)
            #pragma unroll
            for (int i = 0; i < CH; ++i) a8[i] = a_ring[base + i][row];
            #pragma unroll
            for (int i = 0; i < CH; ++i) {
                float z  = dot_seg_rs(s0, w0, b0, b1m) + a8[i];
                float hv = fast_tanh(z);
                h0ring[base + i][wrs] = hv;               // 1 ds_write_b32
                seg_load(s0, &h0ring[base + i][24 * kg]); // readback, 4 b128
            }
            lds_fence();
            if (lane == 0) vf[0] = k + 1;
        }
    } else if (wv == 1) {
        // ================= wave1: p1 projection (no recurrence, prio0) ====
        v2f wp[4][8];
        load_w(wp, Wih1, o, kg);
        const float b1s = bih1[row] + bhh1[row];

        #pragma unroll 1
        for (int k = 0; k < NCH; ++k) {
            while (vf[0] < k + 1) nap();
            if (k >= RCH) { while (vf[2] < k - (RCH - 1)) nap(); }
            compiler_fence();
            const int base = (k & (RCH - 1)) * CH;
            float4 c0[4];
            seg_load(c0, &h0ring[base][24 * kg]);
            #pragma unroll
            for (int i = 0; i < CH; ++i) {
                float4 nx[4];
                if (i < CH - 1) seg_load(nx, &h0ring[base + i + 1][24 * kg]);
                float pv = dot_seg_rs(c0, wp, b0, b1m) + b1s;
                p1ring[base + i][row] = pv;
                if (i < CH - 1) {
                    #pragma unroll
                    for (int c = 0; c < 4; ++c) c0[c] = nx[c];
                }
            }
            lds_fence();
            if (lane == 0) vf[1] = k + 1;
        }
    } else if (wv == 2) {
        // ================= wave2: layer-1 recurrence + MLP (prio1) ========
        v2f w2[4][8];
        load_w(w2, Whh1, o, kg);
        __builtin_amdgcn_s_setprio(1);

        float4 s1[4];
        #pragma unroll
        for (int c = 0; c < 4; ++c) s1[c] = float4{0.f, 0.f, 0.f, 0.f};

        #pragma unroll 1
        for (int k = 0; k < NCH; ++k) {
            while (vf[1] < k + 1) nap();
            compiler_fence();
            const int base = (k & (RCH - 1)) * CH;
            float p[CH];                 // bulk p prefetch (b32, 2-way free)
            #pragma unroll
            for (int i = 0; i < CH; ++i) p[i] = p1ring[base + i][row];
            #pragma unroll
            for (int i = 0; i < CH; ++i) {
                const int t = k * CH + i;
                float z  = dot_seg_rs(s1, w2, b0, b1m) + p[i];
                float hv = fast_tanh(z);
                h1buf[t & 1][wrs] = hv;                   // 1 ds_write_b32
                seg_load(s1, &h1buf[t & 1][24 * kg]);     // readback, 4 b128
            }
            lds_fence();                 // p reads consumed, h1 writes done
            if (lane == 0) vf[2] = k + 1;
        }
        __builtin_amdgcn_s_setprio(0);
        // ---- MLP head: y = relu(h1 @ W1^T + b1) @ W2^T + b2 ----
        float r = 0.f;
        if (lane < 32) {
            float acc = b1[lane];
            const float* w1row = W1 + lane * HID;
            const float* hN    = h1buf[(TLEN - 1) & 1];
            #pragma unroll
            for (int j = 0; j < HID; ++j)
                acc = fmaf(w1row[j], hN[24 * (j >> 4) + (j & 15)], acc);
            r = fmaxf(acc, 0.f) * W2[lane];
        }
        #pragma unroll
        for (int off = 32; off > 0; off >>= 1) r += __shfl_down(r, off);
        if (lane == 0) out[b] = r + b2[0];
    } else {
        // ================= wave3: feeder (x loads + P0 gather, prio0) =====
        #pragma unroll 1
        for (int k = 0; k < NCH; ++k) {
            if (k >= RCH) {              // a_ring slot-reuse guard (wave0)
                while (vf[0] < k - (RCH - 1)) nap();
                compiler_fence();
            }
            const int* xp = xrow + k * CH;
            int xv[CH];
            #pragma unroll
            for (int i = 0; i < CH; ++i)
                xv[i] = xp[i + vz] & (VOCAB - 1);
            float av[CH];
            #pragma unroll
            for (int i = 0; i < CH; ++i)
                av[i] = P0[xv[i] * HID + row];
            const int base = (k & (RCH - 1)) * CH;
            #pragma unroll
            for (int i = 0; i < CH; ++i)
                a_ring[base + i][row] = av[i];
            lds_fence();                 // a_ring writes visible
            if (lane == 0) vf[3] = k + 1;
        }
    }
}

extern "C" void kernel_launch(void* const* d_in, const int* in_sizes, int n_in,
                              void* d_out, int out_size, void* d_ws, size_t ws_size,
                              hipStream_t stream)
{
    const int*   x    = (const int*)d_in[0];
    const float* emb  = (const float*)d_in[1];
    const float* Wih0 = (const float*)d_in[2];
    const float* Whh0 = (const float*)d_in[3];
    const float* bih0 = (const float*)d_in[4];
    const float* bhh0 = (const float*)d_in[5];
    const float* Wih1 = (const float*)d_in[6];
    const float* Whh1 = (const float*)d_in[7];
    const float* bih1 = (const float*)d_in[8];
    const float* bhh1 = (const float*)d_in[9];
    const float* W1   = (const float*)d_in[10];
    const float* b1   = (const float*)d_in[11];
    const float* W2   = (const float*)d_in[12];
    const float* b2   = (const float*)d_in[13];

    float* P0 = (float*)d_ws;   // 512*64*4 = 128 KiB scratch

    hipLaunchKernelGGL(p0_kernel, dim3(VOCAB), dim3(HID), 0, stream,
                       emb, Wih0, bih0, bhh0, P0);
    hipLaunchKernelGGL(rnn_kernel, dim3(BATCH), dim3(256), 0, stream,
                       x, P0, Whh0, Wih1, Whh1, bih1, bhh1,
                       W1, b1, W2, b2, (float*)d_out);
}